// Round 7
// baseline (134.612 us; speedup 1.0000x reference)
//
#include <hip/hip_runtime.h>
#include <math.h>

#define S_NEI 32

// ---------------- transpose 256x256 (WkT[e][f] = Wk[f][e]) ----------------
__global__ __launch_bounds__(256) void transpose256(const float* __restrict__ in,
                                                    float* __restrict__ outT) {
    __shared__ float tile[32][33];
    const int bx = blockIdx.x * 32, by = blockIdx.y * 32;
    const int x = threadIdx.x, y = threadIdx.y;  // 32 x 8
#pragma unroll
    for (int i = 0; i < 32; i += 8)
        tile[y + i][x] = in[(by + y + i) * 256 + bx + x];
    __syncthreads();
#pragma unroll
    for (int i = 0; i < 32; i += 8)
        outT[(bx + y + i) * 256 + by + x] = tile[x][y + i];
}

// ---------------- legacy 8x256 tile GEMM (for tiny precompute GEMMs) -------
template <int KT>
__device__ __forceinline__ void gemm_tile8(const float* __restrict__ A, int row0,
                                           const float* __restrict__ B,
                                           float acc[2][4], float* __restrict__ sA,
                                           float* __restrict__ sB) {
    const int t = threadIdx.x;
    const int tr = t >> 6, tc = t & 63;
    const int r = t >> 5;
    const int k1 = t & 31;
    const size_t arow = (size_t)(row0 + r) * KT;
    for (int kb = 0; kb < KT; kb += 32) {
        sA[k1 * 12 + r] = A[arow + kb + k1];
#pragma unroll
        for (int i = 0; i < 8; ++i) {
            *reinterpret_cast<float4*>(&sB[(i * 4 + tr) * 256 + tc * 4]) =
                *reinterpret_cast<const float4*>(&B[(size_t)(kb + i * 4 + tr) * 256 + tc * 4]);
        }
        __syncthreads();
#pragma unroll
        for (int k = 0; k < 32; ++k) {
            const float2 a2 = *reinterpret_cast<const float2*>(&sA[k * 12 + tr * 2]);
            const float4 b4 = *reinterpret_cast<const float4*>(&sB[k * 256 + tc * 4]);
            acc[0][0] += a2.x * b4.x; acc[0][1] += a2.x * b4.y;
            acc[0][2] += a2.x * b4.z; acc[0][3] += a2.x * b4.w;
            acc[1][0] += a2.y * b4.x; acc[1][1] += a2.y * b4.y;
            acc[1][2] += a2.y * b4.z; acc[1][3] += a2.y * b4.w;
        }
        __syncthreads();
    }
}

// Wqk=Wq@WkT, Wvc=Wv@Wc_top, Wmc=Wm@Wc_bot
__global__ __launch_bounds__(256) void precompute3(const float* __restrict__ Wq,
                                                   const float* __restrict__ Wv,
                                                   const float* __restrict__ Wm,
                                                   const float* __restrict__ Wc,
                                                   const float* __restrict__ WkT,
                                                   float* __restrict__ Wqk,
                                                   float* __restrict__ Wvc,
                                                   float* __restrict__ Wmc) {
    __shared__ float sA[32 * 12];
    __shared__ float sB[32 * 256];
    float acc[2][4] = {};
    const float *Ap, *Bp;
    float* Cp;
    switch (blockIdx.y) {
        case 0: Ap = Wq; Bp = WkT; Cp = Wqk; break;
        case 1: Ap = Wv; Bp = Wc; Cp = Wvc; break;
        default: Ap = Wm; Bp = Wc + 256 * 256; Cp = Wmc; break;
    }
    const int row0 = blockIdx.x * 8;
    gemm_tile8<256>(Ap, row0, Bp, acc, sA, sB);
    const int tr = threadIdx.x >> 6, tc = threadIdx.x & 63;
#pragma unroll
    for (int i = 0; i < 2; ++i) {
        float4 v = make_float4(acc[i][0], acc[i][1], acc[i][2], acc[i][3]);
        *reinterpret_cast<float4*>(&Cp[(row0 + tr * 2 + i) * 256 + tc * 4]) = v;
    }
}

// bqk = bq@WkT ; bfull = bv@Wc_top + bm@Wc_bot + bc  (block per column)
__global__ __launch_bounds__(256) void bias_k(const float* __restrict__ bq,
                                              const float* __restrict__ bv,
                                              const float* __restrict__ bm,
                                              const float* __restrict__ bc,
                                              const float* __restrict__ Wc,
                                              const float* __restrict__ WkT,
                                              float* __restrict__ bqk,
                                              float* __restrict__ bfull) {
    const int c = blockIdx.x;
    const int e = threadIdx.x;
    const int w = e >> 6, l = e & 63;
    float a = bq[e] * WkT[e * 256 + c];
    float v = bv[e] * Wc[e * 256 + c] + bm[e] * Wc[(256 + e) * 256 + c];
    __shared__ float redA[4], redV[4];
#pragma unroll
    for (int off = 32; off; off >>= 1) { a += __shfl_xor(a, off); v += __shfl_xor(v, off); }
    if (l == 0) { redA[w] = a; redV[w] = v; }
    __syncthreads();
    if (e == 0) {
        bqk[c] = redA[0] + redA[1] + redA[2] + redA[3];
        bfull[c] = bc[c] + redV[0] + redV[1] + redV[2] + redV[3];
    }
}

// ---------------- fused per-8-node megakernel, 512 threads -----------------
// wave w: kq = w&3 (K-quarter), ch = w>>2 (column half, 128 cols).
// lane owns 2 adjacent cols (float2 B-stream); acc[8 rows][2 cols].
// Phase 1: Qk = self(8x256)@Wqk + bqk          Phase 2: attn+mean (1 node/wave,
// flash 2x16-chunk)                            Phase 3: out = norm(tanh(AF@Wf+b))
// LDS region R0 aliased: sA -> sP -> sAF -> sP (phase barriers between).
// Bank-skewed transposed layout: word(k,r) = k*12 + (k>>3)*4 + r.

#define SAF(k) ((k) * 12 + (((k) >> 3) << 2))

#define FMAB(a0, a1, b2)                                                    \
    do {                                                                    \
        acc[0][0] += (a0).x * (b2).x; acc[0][1] += (a0).x * (b2).y;         \
        acc[1][0] += (a0).y * (b2).x; acc[1][1] += (a0).y * (b2).y;         \
        acc[2][0] += (a0).z * (b2).x; acc[2][1] += (a0).z * (b2).y;         \
        acc[3][0] += (a0).w * (b2).x; acc[3][1] += (a0).w * (b2).y;         \
        acc[4][0] += (a1).x * (b2).x; acc[4][1] += (a1).x * (b2).y;         \
        acc[5][0] += (a1).y * (b2).x; acc[5][1] += (a1).y * (b2).y;         \
        acc[6][0] += (a1).z * (b2).x; acc[6][1] += (a1).z * (b2).y;         \
        acc[7][0] += (a1).w * (b2).x; acc[7][1] += (a1).w * (b2).y;         \
    } while (0)

__global__ __launch_bounds__(512, 4) void fused8(const float* __restrict__ id2feat,
                                                 const int* __restrict__ nodes,
                                                 const int* __restrict__ neigh_mean,
                                                 const int* __restrict__ neigh_attn,
                                                 const float* __restrict__ Wqk,
                                                 const float* __restrict__ bqk,
                                                 const float* __restrict__ Wfused,
                                                 const float* __restrict__ bfull,
                                                 float* __restrict__ out) {
    // LDS: R0 [0, 25600) aliased sA/sP/sAF; sQk [25600, 33920);
    //      sIA [33920,+1024); sIM [34944,+1024); sN [35968,+64)
    __shared__ __align__(16) char smem[36224];
    float* R0  = (float*)smem;          // sA / sP / sAF
    float* sQk = (float*)(smem + 25600);
    int*   sIA = (int*)(smem + 33920);
    int*   sIM = (int*)(smem + 34944);
    float* sN  = (float*)(smem + 35968);

    const int t = threadIdx.x;          // 512
    const int w = t >> 6, l = t & 63;
    const int kq = w & 3, ch = w >> 2;
    const int c2 = ch * 128 + l * 2;    // this lane's 2 output columns
    const int row0 = blockIdx.x * 8;

    // index staging
    if (t < 256) sIA[t] = neigh_attn[(size_t)row0 * S_NEI + t];
    else sIM[t - 256] = neigh_mean[(size_t)row0 * S_NEI + (t - 256)];

    // stage 8 self rows transposed into sA (one float4 per thread)
    {
        const int r = t & 7;
        const int k0 = (t >> 3) * 4;
        const float4 v = *reinterpret_cast<const float4*>(
            &id2feat[(size_t)nodes[row0 + r] * 256 + k0]);
        R0[SAF(k0 + 0) + r] = v.x;
        R0[SAF(k0 + 1) + r] = v.y;
        R0[SAF(k0 + 2) + r] = v.z;
        R0[SAF(k0 + 3) + r] = v.w;
    }
    __syncthreads();

    float acc[8][2] = {};

    // ---- phase 1: K-quarter [kq*64, +64), cols [c2, c2+2) ----
    {
        const float* Bp = Wqk + (size_t)(kq * 64) * 256 + c2;
        float2 bufA[8], bufB[8];
#pragma unroll
        for (int j = 0; j < 8; ++j)
            bufA[j] = *reinterpret_cast<const float2*>(&Bp[(size_t)j * 256]);
        for (int kb = 0; kb < 64; kb += 16) {
#pragma unroll
            for (int j = 0; j < 8; ++j)
                bufB[j] = *reinterpret_cast<const float2*>(&Bp[(size_t)(kb + 8 + j) * 256]);
#pragma unroll
            for (int j = 0; j < 8; ++j) {
                const int k = kq * 64 + kb + j;
                const float4 a0 = *reinterpret_cast<const float4*>(&R0[SAF(k)]);
                const float4 a1 = *reinterpret_cast<const float4*>(&R0[SAF(k) + 4]);
                FMAB(a0, a1, bufA[j]);
            }
            if (kb + 16 < 64) {
#pragma unroll
                for (int j = 0; j < 8; ++j)
                    bufA[j] = *reinterpret_cast<const float2*>(&Bp[(size_t)(kb + 16 + j) * 256]);
            }
#pragma unroll
            for (int j = 0; j < 8; ++j) {
                const int k = kq * 64 + kb + 8 + j;
                const float4 a0 = *reinterpret_cast<const float4*>(&R0[SAF(k)]);
                const float4 a1 = *reinterpret_cast<const float4*>(&R0[SAF(k) + 4]);
                FMAB(a0, a1, bufB[j]);
            }
        }
    }
    __syncthreads();  // sA dead; sP may be written
    if (kq) {
        float* p = R0 + ((ch * 3 + (kq - 1)) * 8) * 132 + l * 2;
#pragma unroll
        for (int r = 0; r < 8; ++r) {
            p[r * 132 + 0] = acc[r][0];
            p[r * 132 + 1] = acc[r][1];
        }
    }
    __syncthreads();
    if (kq == 0) {
#pragma unroll
        for (int r = 0; r < 8; ++r) {
            float v0 = acc[r][0] + bqk[c2 + 0];
            float v1 = acc[r][1] + bqk[c2 + 1];
#pragma unroll
            for (int s = 0; s < 3; ++s) {
                const float* p = R0 + ((ch * 3 + s) * 8 + r) * 132 + l * 2;
                v0 += p[0]; v1 += p[1];
            }
            sQk[r * 260 + c2 + 0] = v0;
            sQk[r * 260 + c2 + 1] = v1;
        }
    }
    __syncthreads();  // sQk ready; sP dead

    // ---- phase 2: wave w owns node b = w; flash-style 2x16 chunks ----
    {
        const int b = w;
        const float4 q = *reinterpret_cast<const float4*>(&sQk[b * 260 + 4 * l]);
        const float4* f4 = reinterpret_cast<const float4*>(id2feat);
        const int* ia = sIA + b * 32;
        const int* im = sIM + b * 32;
        float4 macc = make_float4(0.f, 0.f, 0.f, 0.f);
        float mch[2], ech[2];
        float4 wch[2];
#pragma unroll
        for (int cch = 0; cch < 2; ++cch) {
            float4 r[16];
#pragma unroll
            for (int j = 0; j < 16; ++j) r[j] = f4[(size_t)ia[cch * 16 + j] * 64 + l];
#pragma unroll
            for (int j = 0; j < 16; ++j) {
                const float4 v = f4[(size_t)im[cch * 16 + j] * 64 + l];
                macc.x += v.x; macc.y += v.y; macc.z += v.z; macc.w += v.w;
            }
            float p[16];
#pragma unroll
            for (int j = 0; j < 16; ++j) {
                float s = q.x * r[j].x + q.y * r[j].y + q.z * r[j].z + q.w * r[j].w;
#pragma unroll
                for (int off = 32; off; off >>= 1) s += __shfl_xor(s, off);
                p[j] = s;
            }
            float m = p[0];
#pragma unroll
            for (int j = 1; j < 16; ++j) m = fmaxf(m, p[j]);
            float e = 0.f;
            float4 wa = make_float4(0.f, 0.f, 0.f, 0.f);
#pragma unroll
            for (int j = 0; j < 16; ++j) {
                const float g = __expf(p[j] - m);
                e += g;
                wa.x += g * r[j].x; wa.y += g * r[j].y;
                wa.z += g * r[j].z; wa.w += g * r[j].w;
            }
            mch[cch] = m; ech[cch] = e; wch[cch] = wa;
        }
        const float m = fmaxf(mch[0], mch[1]);
        const float f0 = __expf(mch[0] - m), f1 = __expf(mch[1] - m);
        const float inv = 1.0f / (ech[0] * f0 + ech[1] * f1);
        const float mix[4] = {(wch[0].x * f0 + wch[1].x * f1) * inv,
                              (wch[0].y * f0 + wch[1].y * f1) * inv,
                              (wch[0].z * f0 + wch[1].z * f1) * inv,
                              (wch[0].w * f0 + wch[1].w * f1) * inv};
        const float mev[4] = {macc.x * (1.f / 32), macc.y * (1.f / 32),
                              macc.z * (1.f / 32), macc.w * (1.f / 32)};
        // write AF transposed: mix -> cols [0,256), mean -> cols [256,512)
#pragma unroll
        for (int c = 0; c < 4; ++c) {
            R0[SAF(4 * l + c) + b] = mix[c];
            R0[SAF(256 + 4 * l + c) + b] = mev[c];
        }
    }
    __syncthreads();  // sAF ready

    // ---- phase 3: K-quarter [kq*128, +128) of AF(8x512)@Wfused ----
#pragma unroll
    for (int r = 0; r < 8; ++r) { acc[r][0] = 0.f; acc[r][1] = 0.f; }
    {
        const float* Bp = Wfused + (size_t)(kq * 128) * 256 + c2;
        float2 bufA[8], bufB[8];
#pragma unroll
        for (int j = 0; j < 8; ++j)
            bufA[j] = *reinterpret_cast<const float2*>(&Bp[(size_t)j * 256]);
        for (int kb = 0; kb < 128; kb += 16) {
#pragma unroll
            for (int j = 0; j < 8; ++j)
                bufB[j] = *reinterpret_cast<const float2*>(&Bp[(size_t)(kb + 8 + j) * 256]);
#pragma unroll
            for (int j = 0; j < 8; ++j) {
                const int k = kq * 128 + kb + j;
                const float4 a0 = *reinterpret_cast<const float4*>(&R0[SAF(k)]);
                const float4 a1 = *reinterpret_cast<const float4*>(&R0[SAF(k) + 4]);
                FMAB(a0, a1, bufA[j]);
            }
            if (kb + 16 < 128) {
#pragma unroll
                for (int j = 0; j < 8; ++j)
                    bufA[j] = *reinterpret_cast<const float2*>(&Bp[(size_t)(kb + 16 + j) * 256]);
            }
#pragma unroll
            for (int j = 0; j < 8; ++j) {
                const int k = kq * 128 + kb + 8 + j;
                const float4 a0 = *reinterpret_cast<const float4*>(&R0[SAF(k)]);
                const float4 a1 = *reinterpret_cast<const float4*>(&R0[SAF(k) + 4]);
                FMAB(a0, a1, bufB[j]);
            }
        }
    }
    __syncthreads();  // sAF dead; sP may be written
    if (kq) {
        float* p = R0 + ((ch * 3 + (kq - 1)) * 8) * 132 + l * 2;
#pragma unroll
        for (int r = 0; r < 8; ++r) {
            p[r * 132 + 0] = acc[r][0];
            p[r * 132 + 1] = acc[r][1];
        }
    }
    __syncthreads();
    float v[8][2];
    if (kq == 0) {
#pragma unroll
        for (int r = 0; r < 8; ++r) {
            float v0 = acc[r][0] + bfull[c2 + 0];
            float v1 = acc[r][1] + bfull[c2 + 1];
#pragma unroll
            for (int s = 0; s < 3; ++s) {
                const float* p = R0 + ((ch * 3 + s) * 8 + r) * 132 + l * 2;
                v0 += p[0]; v1 += p[1];
            }
            v[r][0] = tanhf(v0);
            v[r][1] = tanhf(v1);
        }
        float sq[8];
#pragma unroll
        for (int r = 0; r < 8; ++r) {
            float s = v[r][0] * v[r][0] + v[r][1] * v[r][1];
#pragma unroll
            for (int off = 32; off; off >>= 1) s += __shfl_xor(s, off);
            sq[r] = s;
        }
        if (l < 8) sN[ch * 8 + l] = sq[l];
    }
    __syncthreads();
    if (kq == 0) {
#pragma unroll
        for (int r = 0; r < 8; ++r) {
            const float S = sN[r] + sN[8 + r];
            const float invn = 1.0f / fmaxf(sqrtf(S), 1e-12f);
            *reinterpret_cast<float2*>(&out[(size_t)(row0 + r) * 256 + c2]) =
                make_float2(v[r][0] * invn, v[r][1] * invn);
        }
    }
}

extern "C" void kernel_launch(void* const* d_in, const int* in_sizes, int n_in,
                              void* d_out, int out_size, void* d_ws, size_t ws_size,
                              hipStream_t stream) {
    const int* nodes      = (const int*)d_in[0];
    const int* neigh_mean = (const int*)d_in[1];
    const int* neigh_attn = (const int*)d_in[2];
    const float* id2feat  = (const float*)d_in[3];
    const float* Wm = (const float*)d_in[4];
    const float* bm = (const float*)d_in[5];
    const float* Wq = (const float*)d_in[6];
    const float* bq = (const float*)d_in[7];
    const float* Wk = (const float*)d_in[8];
    // d_in[9] = bk: cancels in softmax
    const float* Wv = (const float*)d_in[10];
    const float* bv = (const float*)d_in[11];
    const float* Wc = (const float*)d_in[12];
    const float* bc = (const float*)d_in[13];
    float* out = (float*)d_out;

    const int B = in_sizes[0];  // 4096

    float* ws    = (float*)d_ws;
    float* WkT   = ws;                 // 65536
    float* Wqk   = ws + 65536;         // 65536
    float* Wvc   = ws + 131072;        // 65536 } contiguous Wfused[512][256]
    float* Wmc   = ws + 196608;        // 65536 }
    float* bqk   = ws + 262144;        // 256
    float* bfull = ws + 262400;        // 256

    transpose256<<<dim3(8, 8), dim3(32, 8), 0, stream>>>(Wk, WkT);
    precompute3<<<dim3(32, 3), 256, 0, stream>>>(Wq, Wv, Wm, Wc, WkT, Wqk, Wvc, Wmc);
    bias_k<<<256, 256, 0, stream>>>(bq, bv, bm, bc, Wc, WkT, bqk, bfull);
    fused8<<<B / 8, 512, 0, stream>>>(id2feat, nodes, neigh_mean, neigh_attn,
                                      Wqk, bqk, Wvc /*Wfused*/, bfull, out);
}